// Round 2
// baseline (598.615 us; speedup 1.0000x reference)
//
#include <hip/hip_runtime.h>
#include <stdint.h>

typedef float  f32x4  __attribute__((ext_vector_type(4)));
typedef short  bf16x8 __attribute__((ext_vector_type(8)));

#define TYPES 10
#define D_IN  128
#define D_H1  512
#define D_H2  512
#define D_OUT 256

__device__ __forceinline__ unsigned short f2bf(float f) {
  union { float f; unsigned u; } v; v.f = f;
  unsigned u = v.u;
  return (unsigned short)((u + 0x7FFFu + ((u >> 16) & 1u)) >> 16);  // RTNE
}

__device__ __forceinline__ void async16(void* lds, const void* g) {
  __builtin_amdgcn_global_load_lds(
      (const __attribute__((address_space(1))) void*)g,
      (__attribute__((address_space(3))) void*)lds, 16, 0, 0);
}

// meta layout (ints): [0..9] counts, [16..26] padded offsets (offs[10]=total), [32..41] scatter cursors
__global__ void k_init(int* meta) {
  if (threadIdx.x < 48) meta[threadIdx.x] = 0;
}

__global__ void k_hist(const int* __restrict__ types, int n, int* __restrict__ meta) {
  __shared__ int lc[TYPES];
  if (threadIdx.x < TYPES) lc[threadIdx.x] = 0;
  __syncthreads();
  int i = blockIdx.x * 256 + threadIdx.x;
  if (i < n) atomicAdd(&lc[types[i]], 1);
  __syncthreads();
  if (threadIdx.x < TYPES && lc[threadIdx.x]) atomicAdd(&meta[threadIdx.x], lc[threadIdx.x]);
}

__global__ void k_scan(int* meta) {
  if (threadIdx.x == 0) {
    int off = 0;
    for (int t = 0; t < TYPES; ++t) {
      meta[16 + t] = off;
      off += ((meta[t] + 127) >> 7) << 7;   // pad each segment to 128 rows
    }
    meta[26] = off;                          // padded total
  }
}

__global__ void k_scatter(const int* __restrict__ types, int n,
                          int* __restrict__ meta, int* __restrict__ perm) {
  __shared__ int lc[TYPES], lbase[TYPES];
  if (threadIdx.x < TYPES) lc[threadIdx.x] = 0;
  __syncthreads();
  int i = blockIdx.x * 256 + threadIdx.x;
  int t = 0, loc = 0;
  bool ok = i < n;
  if (ok) { t = types[i]; loc = atomicAdd(&lc[t], 1); }
  __syncthreads();
  if (threadIdx.x < TYPES) {
    int c = lc[threadIdx.x];
    lbase[threadIdx.x] = c ? atomicAdd(&meta[32 + threadIdx.x], c) : 0;
  }
  __syncthreads();
  if (ok) perm[meta[16 + t] + lbase[t] + loc] = i;
}

// gather rows into sorted order, fp32 -> bf16; zero the padding rows
__global__ void k_gather(const float* __restrict__ x, const int* __restrict__ perm,
                         const int* __restrict__ meta, unsigned short* __restrict__ xs) {
  int p = blockIdx.x * 8 + (threadIdx.x >> 5);
  if (p >= meta[26]) return;
  int t = 0;
  while (p >= meta[17 + t]) t++;
  int e = (threadIdx.x & 31) * 4;
  unsigned short o0, o1, o2, o3;
  if (p - meta[16 + t] < meta[t]) {
    const float4 v = *(const float4*)(x + (size_t)perm[p] * D_IN + e);
    o0 = f2bf(v.x); o1 = f2bf(v.y); o2 = f2bf(v.z); o3 = f2bf(v.w);
  } else {
    o0 = o1 = o2 = o3 = 0;
  }
  *(ushort4*)(xs + (size_t)p * D_IN + e) = make_ushort4(o0, o1, o2, o3);
}

// W[t] (K x NOUT) fp32 -> Wt[t] (NOUT x K) bf16, 64x64 LDS tiles
__global__ void k_wtrans(const float* __restrict__ W, unsigned short* __restrict__ Wt,
                         int K, int NOUT) {
  int t = blockIdx.y;
  int ntn = NOUT >> 6;
  int kb = blockIdx.x / ntn, nb = blockIdx.x % ntn;
  __shared__ unsigned short tile[64][65];
  const float* src = W + (size_t)t * K * NOUT + (size_t)(kb * 64) * NOUT + nb * 64;
  int c = threadIdx.x & 63;
  int r0 = threadIdx.x >> 6;
  #pragma unroll
  for (int i = 0; i < 16; ++i) {
    int r = r0 * 16 + i;
    tile[r][c] = f2bf(src[(size_t)r * NOUT + c]);
  }
  __syncthreads();
  unsigned short* dst = Wt + (size_t)t * NOUT * K + (size_t)(nb * 64) * K + kb * 64;
  #pragma unroll
  for (int i = 0; i < 16; ++i) {
    int nn = r0 * 16 + i;
    dst[(size_t)nn * K + c] = tile[c][nn];
  }
}

// Grouped GEMM over sorted rows. A: [NPAD][K] bf16 row-major. Wt: [10][NOUT][K] bf16.
// 128x128 tile, BK=64, double-buffered LDS (2-phase T3-minimum pipeline),
// XOR-swizzled LDS (byte ^= (row&7)<<4) applied via pre-swizzled global source
// (global_load_lds writes linearly -> permute source granule, same XOR on ds_read).
// 4 waves (2x2), each 64x64 output via 4x4 16x16x32 bf16 MFMA frags.
template <int K, int NOUT, bool RELU, bool FINAL>
__launch_bounds__(256)
__global__ void k_gemm(const unsigned short* __restrict__ A,
                       const unsigned short* __restrict__ Wt,
                       const float* __restrict__ bias,
                       unsigned short* __restrict__ H,
                       float* __restrict__ OUT,
                       const int* __restrict__ meta,
                       const int* __restrict__ perm) {
  __shared__ char lds[65536];   // [buf][A 16K | B 16K] x2

  // bijective XCD-aware swizzle (m204): keep blocks sharing an A row-panel
  // (consecutive raw ids, x-fastest) on the same XCD.
  int NXB = gridDim.x;
  int nwg = NXB * (int)gridDim.y;
  int raw = blockIdx.x + blockIdx.y * NXB;
  int q = nwg >> 3, rr = nwg & 7;
  int xcd = raw & 7, idx = raw >> 3;
  int swz = (xcd < rr ? xcd * (q + 1) : rr * (q + 1) + (xcd - rr) * q) + idx;
  int bx = swz % NXB, by = swz / NXB;

  int row0 = by * 128;
  if (row0 >= meta[26]) return;
  int t = 0;
  while (row0 >= meta[17 + t]) t++;          // segment offsets are multiples of 128
  int seg = meta[16 + t], cnt = meta[t];
  int tid = threadIdx.x, lane = tid & 63, wid = tid >> 6;
  int wr = (wid >> 1) * 64, wc = (wid & 1) * 64;
  int col0 = bx * 128;
  const char* Ag = (const char*)(A + (size_t)row0 * K);
  const char* Bg = (const char*)(Wt + ((size_t)t * NOUT + col0) * K);

  // staging precompute: thread covers row = i*32 + (tid>>3), granule sg = tid&7 of
  // the 128B k-slice; source granule pre-swizzled: sg ^ (row&7).
  int srow = tid >> 3, sg = tid & 7;
  const char* aSrc[4]; const char* bSrc[4]; int ldst[4];
  #pragma unroll
  for (int i = 0; i < 4; ++i) {
    int r = i * 32 + srow;
    int g = sg ^ (r & 7);
    aSrc[i] = Ag + (size_t)r * (K * 2) + g * 16;
    bSrc[i] = Bg + (size_t)r * (K * 2) + g * 16;
    ldst[i] = i * 4096 + (tid >> 6) * 1024;   // wave-uniform base; HW adds lane*16
  }

  f32x4 acc[4][4] = {};
  int rA = lane & 15, qk = lane >> 4;

  // prologue: stage tile 0 into buf 0
  #pragma unroll
  for (int i = 0; i < 4; ++i) {
    async16(lds + ldst[i],         aSrc[i]);
    async16(lds + 16384 + ldst[i], bSrc[i]);
  }
  __syncthreads();

  constexpr int nK = K / 64;
  for (int kt = 0; kt < nK; ++kt) {
    int cur = kt & 1;
    if (kt + 1 < nK) {                        // issue next tile BEFORE compute
      char* nb_ = lds + (cur ^ 1) * 32768;
      #pragma unroll
      for (int i = 0; i < 4; ++i) {
        async16(nb_ + ldst[i],         aSrc[i] + (size_t)(kt + 1) * 128);
        async16(nb_ + 16384 + ldst[i], bSrc[i] + (size_t)(kt + 1) * 128);
      }
    }
    const char* Ab = lds + cur * 32768;
    const char* Bb = Ab + 16384;
    #pragma unroll
    for (int kk = 0; kk < 2; ++kk) {
      bf16x8 a[4], b[4];
      #pragma unroll
      for (int m = 0; m < 4; ++m) {
        int row = wr + m * 16 + rA;
        int off = (row * 128 + kk * 64 + qk * 16) ^ ((rA & 7) << 4);
        a[m] = *(const bf16x8*)(Ab + off);
      }
      #pragma unroll
      for (int n = 0; n < 4; ++n) {
        int row = wc + n * 16 + rA;
        int off = (row * 128 + kk * 64 + qk * 16) ^ ((rA & 7) << 4);
        b[n] = *(const bf16x8*)(Bb + off);
      }
      #pragma unroll
      for (int m = 0; m < 4; ++m)
        #pragma unroll
        for (int n = 0; n < 4; ++n)
          acc[m][n] = __builtin_amdgcn_mfma_f32_16x16x32_bf16(a[m], b[n], acc[m][n], 0, 0, 0);
    }
    __syncthreads();   // drains vmcnt(0): next tile's loads had the whole compute to land
  }

  // epilogue: D mapping col=lane&15, row=(lane>>4)*4+e (measured, learn_hip m89/m91)
  int cA = lane & 15, rE = (lane >> 4) * 4;
  #pragma unroll
  for (int n = 0; n < 4; ++n) {
    int col = col0 + wc + n * 16 + cA;
    float bv = bias[t * NOUT + col];
    #pragma unroll
    for (int m = 0; m < 4; ++m) {
      int rb = row0 + wr + m * 16 + rE;
      #pragma unroll
      for (int e = 0; e < 4; ++e) {
        float v = acc[m][n][e] + bv;
        if (RELU) v = fmaxf(v, 0.f);
        if (!FINAL) {
          H[(size_t)(rb + e) * NOUT + col] = f2bf(v);
        } else {
          int r = rb + e;
          if (r - seg < cnt) OUT[(size_t)perm[r] * NOUT + col] = v;
        }
      }
    }
  }
}

extern "C" void kernel_launch(void* const* d_in, const int* in_sizes, int n_in,
                              void* d_out, int out_size, void* d_ws, size_t ws_size,
                              hipStream_t stream) {
  const float* x     = (const float*)d_in[0];
  const int*   types = (const int*)d_in[1];
  const float* W0    = (const float*)d_in[2];
  const float* b0    = (const float*)d_in[3];
  const float* W1    = (const float*)d_in[4];
  const float* b1    = (const float*)d_in[5];
  const float* W2    = (const float*)d_in[6];
  const float* b2    = (const float*)d_in[7];
  float* out = (float*)d_out;
  int n = in_sizes[1];
  int RB = (n + 127) / 128 + TYPES;       // worst-case padded row blocks
  size_t NPAD = (size_t)RB * 128;

  char* ws = (char*)d_ws;
  int* meta = (int*)ws;
  int* perm = (int*)(ws + 1024);
  size_t off = 1024 + NPAD * 4;
  off = (off + 255) & ~(size_t)255;
  unsigned short* wt0 = (unsigned short*)(ws + off); off += (size_t)TYPES * D_H1 * D_IN * 2;
  unsigned short* wt1 = (unsigned short*)(ws + off); off += (size_t)TYPES * D_H2 * D_H1 * 2;
  unsigned short* wt2 = (unsigned short*)(ws + off); off += (size_t)TYPES * D_OUT * D_H2 * 2;
  off = (off + 255) & ~(size_t)255;
  unsigned short* B1 = (unsigned short*)(ws + off); off += NPAD * 512 * 2;  // xs, later h2
  unsigned short* B2 = (unsigned short*)(ws + off); off += NPAD * 512 * 2;  // h1

  int hb = (n + 255) / 256;
  k_init<<<1, 64, 0, stream>>>(meta);
  k_hist<<<hb, 256, 0, stream>>>(types, n, meta);
  k_scan<<<1, 64, 0, stream>>>(meta);
  k_scatter<<<hb, 256, 0, stream>>>(types, n, meta, perm);
  k_gather<<<RB * 16, 256, 0, stream>>>(x, perm, meta, B1);
  k_wtrans<<<dim3((D_IN / 64) * (D_H1 / 64), TYPES), 256, 0, stream>>>(W0, wt0, D_IN, D_H1);
  k_wtrans<<<dim3((D_H1 / 64) * (D_H2 / 64), TYPES), 256, 0, stream>>>(W1, wt1, D_H1, D_H2);
  k_wtrans<<<dim3((D_H2 / 64) * (D_OUT / 64), TYPES), 256, 0, stream>>>(W2, wt2, D_H2, D_OUT);

  k_gemm<D_IN, D_H1, true,  false><<<dim3(D_H1 / 128, RB), 256, 0, stream>>>(B1, wt0, b0, B2, nullptr, meta, perm);
  k_gemm<D_H1, D_H2, true,  false><<<dim3(D_H2 / 128, RB), 256, 0, stream>>>(B2, wt1, b1, B1, nullptr, meta, perm);
  k_gemm<D_H2, D_OUT, false, true ><<<dim3(D_OUT / 128, RB), 256, 0, stream>>>(B1, wt2, b2, nullptr, out, meta, perm);
}

// Round 4
// 542.371 us; speedup vs baseline: 1.1037x; 1.1037x over previous
//
#include <hip/hip_runtime.h>
#include <stdint.h>

typedef float  f32x4  __attribute__((ext_vector_type(4)));
typedef short  bf16x8 __attribute__((ext_vector_type(8)));

#define TYPES 10
#define D_IN  128
#define D_H1  512
#define D_H2  512
#define D_OUT 256

__device__ __forceinline__ unsigned short f2bf(float f) {
  union { float f; unsigned u; } v; v.f = f;
  unsigned u = v.u;
  return (unsigned short)((u + 0x7FFFu + ((u >> 16) & 1u)) >> 16);  // RTNE
}

__device__ __forceinline__ void async16(void* lds, const void* g) {
  __builtin_amdgcn_global_load_lds(
      (const __attribute__((address_space(1))) void*)g,
      (__attribute__((address_space(3))) void*)lds, 16, 0, 0);
}

// meta layout (ints): [0..9] counts, [16..26] padded offsets (offs[10]=total), [32..41] scatter cursors
__global__ void k_init(int* meta) {
  if (threadIdx.x < 48) meta[threadIdx.x] = 0;
}

__global__ void k_hist(const int* __restrict__ types, int n, int* __restrict__ meta) {
  __shared__ int lc[TYPES];
  if (threadIdx.x < TYPES) lc[threadIdx.x] = 0;
  __syncthreads();
  int i = blockIdx.x * 256 + threadIdx.x;
  if (i < n) atomicAdd(&lc[types[i]], 1);
  __syncthreads();
  if (threadIdx.x < TYPES && lc[threadIdx.x]) atomicAdd(&meta[threadIdx.x], lc[threadIdx.x]);
}

__global__ void k_scan(int* meta) {
  if (threadIdx.x == 0) {
    int off = 0;
    for (int t = 0; t < TYPES; ++t) {
      meta[16 + t] = off;
      off += ((meta[t] + 255) >> 8) << 8;   // pad each segment to 256 rows (BM=256)
    }
    meta[26] = off;                          // padded total
  }
}

__global__ void k_scatter(const int* __restrict__ types, int n,
                          int* __restrict__ meta, int* __restrict__ perm) {
  __shared__ int lc[TYPES], lbase[TYPES];
  if (threadIdx.x < TYPES) lc[threadIdx.x] = 0;
  __syncthreads();
  int i = blockIdx.x * 256 + threadIdx.x;
  int t = 0, loc = 0;
  bool ok = i < n;
  if (ok) { t = types[i]; loc = atomicAdd(&lc[t], 1); }
  __syncthreads();
  if (threadIdx.x < TYPES) {
    int c = lc[threadIdx.x];
    lbase[threadIdx.x] = c ? atomicAdd(&meta[32 + threadIdx.x], c) : 0;
  }
  __syncthreads();
  if (ok) perm[meta[16 + t] + lbase[t] + loc] = i;
}

// gather rows into sorted order, fp32 -> bf16; zero the padding rows
__global__ void k_gather(const float* __restrict__ x, const int* __restrict__ perm,
                         const int* __restrict__ meta, unsigned short* __restrict__ xs) {
  int p = blockIdx.x * 8 + (threadIdx.x >> 5);
  if (p >= meta[26]) return;
  int t = 0;
  while (p >= meta[17 + t]) t++;
  int e = (threadIdx.x & 31) * 4;
  unsigned short o0, o1, o2, o3;
  if (p - meta[16 + t] < meta[t]) {
    const float4 v = *(const float4*)(x + (size_t)perm[p] * D_IN + e);
    o0 = f2bf(v.x); o1 = f2bf(v.y); o2 = f2bf(v.z); o3 = f2bf(v.w);
  } else {
    o0 = o1 = o2 = o3 = 0;
  }
  *(ushort4*)(xs + (size_t)p * D_IN + e) = make_ushort4(o0, o1, o2, o3);
}

// W[t] (K x NOUT) fp32 -> Wt[t] (NOUT x K) bf16, 64x64 LDS tiles
__global__ void k_wtrans(const float* __restrict__ W, unsigned short* __restrict__ Wt,
                         int K, int NOUT) {
  int t = blockIdx.y;
  int ntn = NOUT >> 6;
  int kb = blockIdx.x / ntn, nb = blockIdx.x % ntn;
  __shared__ unsigned short tile[64][65];
  const float* src = W + (size_t)t * K * NOUT + (size_t)(kb * 64) * NOUT + nb * 64;
  int c = threadIdx.x & 63;
  int r0 = threadIdx.x >> 6;
  #pragma unroll
  for (int i = 0; i < 16; ++i) {
    int r = r0 * 16 + i;
    tile[r][c] = f2bf(src[(size_t)r * NOUT + c]);
  }
  __syncthreads();
  unsigned short* dst = Wt + (size_t)t * NOUT * K + (size_t)(nb * 64) * K + kb * 64;
  #pragma unroll
  for (int i = 0; i < 16; ++i) {
    int nn = r0 * 16 + i;
    dst[(size_t)nn * K + c] = tile[c][nn];
  }
}

// ---------------------------------------------------------------------------
// Grouped GEMM, 8-phase counted-vmcnt schedule, 256x256 tile, BK=64,
// 512 threads = 8 waves (2Mx4N), per-wave 128x64 output.
// LDS 128KB: A units [dbuf][mh] 16KB at 0..64K, B units [dbuf][nh] at 64K..128K.
// A unit mh: global rows r with bit6(r)=mh, logical lr=(r&63)|(bit7(r)<<6).
// B unit nh: global cols c with bit5(c)=nh, logical cl=(c&31)|((c>>6)<<5).
// Quadrant order rel->(mh,nh): (0,0),(1,0),(1,1),(0,1).
//   => unit last-read phases in group kt: A0@4kt+3, A1@4kt+2, B0@4kt+1, B1@4kt+3.
// Stage cadence (one unit/phase): group g rel0->A0(g+1), rel1->B1(g+1),
//   rel2->B0(g+2), rel3->A1(g+2)  => stage phases A0@4kt-4, B1@4kt-3,
//   B0@4kt-6, A1@4kt-5: every restage is >=1 phase AFTER its slot's last read
//   (cross-wave safe via the intervening barrier; fixes the R3 A1 same-phase race).
// Group-end wait: vmcnt(4) steady (B0/A1 of g+2 in flight), vmcnt(0) when absent.
// Raw s_barrier (never __syncthreads -> would drain vmcnt). XOR swizzle
// byte^=(lr&7)<<4 via pre-swizzled global source granule (0 conflicts, R2-verified).
// ---------------------------------------------------------------------------
template <int K, int NOUT, bool RELU, bool FINAL>
__launch_bounds__(512, 2)
__global__ void k_gemm(const unsigned short* __restrict__ A,
                       const unsigned short* __restrict__ Wt,
                       const float* __restrict__ bias,
                       unsigned short* __restrict__ H,
                       float* __restrict__ OUT,
                       const int* __restrict__ meta,
                       const int* __restrict__ perm) {
  constexpr int nKT = K / 64;
  __shared__ char lds[131072];

  // bijective XCD-aware swizzle (m204)
  int NXB = gridDim.x;
  int nwg = NXB * (int)gridDim.y;
  int raw = blockIdx.x + blockIdx.y * NXB;
  int q = nwg >> 3, rr = nwg & 7;
  int xcd = raw & 7, idx = raw >> 3;
  int swz = (xcd < rr ? xcd * (q + 1) : rr * (q + 1) + (xcd - rr) * q) + idx;
  int bx = swz % NXB, by = swz / NXB;

  int row0 = by * 256;
  if (row0 >= meta[26]) return;          // block-uniform early exit (before any barrier)
  int t = 0;
  while (row0 >= meta[17 + t]) t++;      // segment offsets are multiples of 256
  int seg = meta[16 + t], cnt = meta[t];
  int tid = threadIdx.x, lane = tid & 63, wid = tid >> 6;
  int wr = (wid >> 2) * 128, wc = (wid & 3) * 64;
  int col0 = bx * 256;
  const char* Ag = (const char*)(A + (size_t)row0 * K);
  const char* Bg = (const char*)(Wt + ((size_t)t * NOUT + col0) * K);

  // staging: thread covers LDS bytes tid*16 (+8192 for j=1) of a unit.
  // LDS pos -> logical row lr = tid>>3, granule gl = tid&7; source granule gl^(lr&7).
  int gsrc = ((tid & 7) ^ ((tid >> 3) & 7)) * 16;
  const char* aS = Ag + (size_t)(tid >> 3) * (2 * K) + gsrc;
  const char* bS = Bg + (size_t)(((tid >> 3) & 31) + ((tid >> 3) >> 5) * 64) * (2 * K) + gsrc;

  // sub: 0=A0, 1=A1, 2=B0, 3=B1 (h = sub&1)
  auto stage = [&](int kt, int sub) {
    if (kt >= nKT) return;
    int h = sub & 1, du = kt & 1;
    char* dst = lds + ((sub < 2) ? 0 : 65536) + (du * 2 + h) * 16384 + wid * 1024;
    const char* src = (sub < 2 ? aS + (size_t)(h * 64) * (2 * K)
                               : bS + (size_t)(h * 32) * (2 * K)) + (size_t)kt * 128;
    async16(dst,        src);
    async16(dst + 8192, src + (size_t)128 * (2 * K));   // j=1: +128 rows / +128 cols
  };

  f32x4 acc[8][4] = {};
  int rA = lane & 15, qoff = (lane >> 4) * 16, xr = (lane & 7) << 4;
  int lrA = (wid >> 2) * 64;   // wave's A logical-row base
  int clB = (wid & 3) * 32;    // wave's B logical-col base

  // prologue, in schedule-phase order (keeps vmcnt prefix semantics):
  stage(0, 2); stage(0, 1); stage(0, 0); stage(0, 3); stage(1, 2); stage(1, 1);
  asm volatile("s_waitcnt vmcnt(4)" ::: "memory");      // group 0's 4 units landed
  __builtin_amdgcn_s_barrier();

  for (int g = 0; g < nKT; ++g) {
    int d = g & 1;
    const char* Ad = lds + d * 32768;
    const char* Bd = lds + 65536 + d * 32768;
    #pragma unroll
    for (int rel = 0; rel < 4; ++rel) {
      constexpr int MH[4] = {0, 1, 1, 0};
      constexpr int NH[4] = {0, 0, 1, 1};
      const int mh = MH[rel], nh = NH[rel];
      const char* Au = Ad + mh * 16384;
      const char* Bu = Bd + nh * 16384;
      bf16x8 a[4][2], b[2][2];
      #pragma unroll
      for (int m = 0; m < 4; ++m) {
        int lr = lrA + m * 16 + rA;
        #pragma unroll
        for (int kk = 0; kk < 2; ++kk)
          a[m][kk] = *(const bf16x8*)(Au + ((lr * 128 + kk * 64 + qoff) ^ xr));
      }
      #pragma unroll
      for (int nn = 0; nn < 2; ++nn) {
        int cl = clB + nn * 16 + rA;
        #pragma unroll
        for (int kk = 0; kk < 2; ++kk)
          b[nn][kk] = *(const bf16x8*)(Bu + ((cl * 128 + kk * 64 + qoff) ^ xr));
      }
      if      (rel == 0) stage(g + 1, 0);   // A0(g+1): slot last read g-1 rel3
      else if (rel == 1) stage(g + 1, 3);   // B1(g+1): slot last read g-1 rel3
      else if (rel == 2) stage(g + 2, 2);   // B0(g+2): slot last read g   rel1
      else               stage(g + 2, 1);   // A1(g+2): slot last read g   rel2
      __builtin_amdgcn_s_barrier();
      asm volatile("s_waitcnt lgkmcnt(0)" ::: "memory");
      __builtin_amdgcn_sched_barrier(0);    // rule 18: pin MFMA after the wait
      __builtin_amdgcn_s_setprio(1);
      #pragma unroll
      for (int kk = 0; kk < 2; ++kk)
        #pragma unroll
        for (int m = 0; m < 4; ++m)
          #pragma unroll
          for (int nn = 0; nn < 2; ++nn)
            acc[mh * 4 + m][nh * 2 + nn] = __builtin_amdgcn_mfma_f32_16x16x32_bf16(
                a[m][kk], b[nn][kk], acc[mh * 4 + m][nh * 2 + nn], 0, 0, 0);
      __builtin_amdgcn_s_setprio(0);
      if (rel == 3 && g + 1 < nKT) {
        if (g + 2 < nKT) asm volatile("s_waitcnt vmcnt(4)" ::: "memory");
        else             asm volatile("s_waitcnt vmcnt(0)" ::: "memory");
      }
      __builtin_amdgcn_s_barrier();
    }
  }

  // epilogue: D mapping col=lane&15, row=(lane>>4)*4+e (measured, learn_hip m89/m91)
  int cA = lane & 15, rE = (lane >> 4) * 4;
  #pragma unroll
  for (int ni = 0; ni < 4; ++ni) {
    int col = col0 + wc + ni * 16 + cA;
    float bv = bias[t * NOUT + col];
    #pragma unroll
    for (int mi = 0; mi < 8; ++mi) {
      int rb = row0 + wr + mi * 16 + rE;
      #pragma unroll
      for (int e = 0; e < 4; ++e) {
        float v = acc[mi][ni][e] + bv;
        if (RELU) v = fmaxf(v, 0.f);
        if (!FINAL) {
          H[(size_t)(rb + e) * NOUT + col] = f2bf(v);
        } else {
          int r = rb + e;
          if (r - seg < cnt) OUT[(size_t)perm[r] * NOUT + col] = v;
        }
      }
    }
  }
}

extern "C" void kernel_launch(void* const* d_in, const int* in_sizes, int n_in,
                              void* d_out, int out_size, void* d_ws, size_t ws_size,
                              hipStream_t stream) {
  const float* x     = (const float*)d_in[0];
  const int*   types = (const int*)d_in[1];
  const float* W0    = (const float*)d_in[2];
  const float* b0    = (const float*)d_in[3];
  const float* W1    = (const float*)d_in[4];
  const float* b1    = (const float*)d_in[5];
  const float* W2    = (const float*)d_in[6];
  const float* b2    = (const float*)d_in[7];
  float* out = (float*)d_out;
  int n = in_sizes[1];
  int RB = (n + 255) / 256 + TYPES;       // worst-case padded 256-row blocks
  size_t NPAD = (size_t)RB * 256;

  char* ws = (char*)d_ws;
  int* meta = (int*)ws;
  int* perm = (int*)(ws + 1024);
  size_t off = 1024 + NPAD * 4;
  off = (off + 255) & ~(size_t)255;
  unsigned short* wt0 = (unsigned short*)(ws + off); off += (size_t)TYPES * D_H1 * D_IN * 2;
  unsigned short* wt1 = (unsigned short*)(ws + off); off += (size_t)TYPES * D_H2 * D_H1 * 2;
  unsigned short* wt2 = (unsigned short*)(ws + off); off += (size_t)TYPES * D_OUT * D_H2 * 2;
  off = (off + 255) & ~(size_t)255;
  unsigned short* B1 = (unsigned short*)(ws + off); off += NPAD * 512 * 2;  // xs, later h2
  unsigned short* B2 = (unsigned short*)(ws + off); off += NPAD * 512 * 2;  // h1

  int hb = (n + 255) / 256;
  k_init<<<1, 64, 0, stream>>>(meta);
  k_hist<<<hb, 256, 0, stream>>>(types, n, meta);
  k_scan<<<1, 64, 0, stream>>>(meta);
  k_scatter<<<hb, 256, 0, stream>>>(types, n, meta, perm);
  k_gather<<<RB * 32, 256, 0, stream>>>(x, perm, meta, B1);
  k_wtrans<<<dim3((D_IN / 64) * (D_H1 / 64), TYPES), 256, 0, stream>>>(W0, wt0, D_IN, D_H1);
  k_wtrans<<<dim3((D_H1 / 64) * (D_H2 / 64), TYPES), 256, 0, stream>>>(W1, wt1, D_H1, D_H2);
  k_wtrans<<<dim3((D_H2 / 64) * (D_OUT / 64), TYPES), 256, 0, stream>>>(W2, wt2, D_H2, D_OUT);

  k_gemm<D_IN, D_H1, true,  false><<<dim3(D_H1 / 256, RB), 512, 0, stream>>>(B1, wt0, b0, B2, nullptr, meta, perm);
  k_gemm<D_H1, D_H2, true,  false><<<dim3(D_H2 / 256, RB), 512, 0, stream>>>(B2, wt1, b1, B1, nullptr, meta, perm);
  k_gemm<D_H2, D_OUT, false, true ><<<dim3(D_OUT / 256, RB), 512, 0, stream>>>(B1, wt2, b2, nullptr, out, meta, perm);
}

// Round 5
// 435.613 us; speedup vs baseline: 1.3742x; 1.2451x over previous
//
#include <hip/hip_runtime.h>
#include <stdint.h>

typedef float  f32x4  __attribute__((ext_vector_type(4)));
typedef short  bf16x8 __attribute__((ext_vector_type(8)));

#define TYPES 10
#define D_IN  128
#define D_H1  512
#define D_H2  512
#define D_OUT 256

__device__ __forceinline__ unsigned short f2bf(float f) {
  union { float f; unsigned u; } v; v.f = f;
  unsigned u = v.u;
  return (unsigned short)((u + 0x7FFFu + ((u >> 16) & 1u)) >> 16);  // RTNE
}

__device__ __forceinline__ void async16(void* lds, const void* g) {
  __builtin_amdgcn_global_load_lds(
      (const __attribute__((address_space(1))) void*)g,
      (__attribute__((address_space(3))) void*)lds, 16, 0, 0);
}

// meta layout (ints): [0..9] counts, [16..26] padded offsets (offs[10]=total), [32..41] scatter cursors
__global__ void k_init(int* meta) {
  if (threadIdx.x < 48) meta[threadIdx.x] = 0;
}

__global__ void k_hist(const int* __restrict__ types, int n, int* __restrict__ meta) {
  __shared__ int lc[TYPES];
  if (threadIdx.x < TYPES) lc[threadIdx.x] = 0;
  __syncthreads();
  int i = blockIdx.x * 256 + threadIdx.x;
  if (i < n) atomicAdd(&lc[types[i]], 1);
  __syncthreads();
  if (threadIdx.x < TYPES && lc[threadIdx.x]) atomicAdd(&meta[threadIdx.x], lc[threadIdx.x]);
}

__global__ void k_scan(int* meta) {
  if (threadIdx.x == 0) {
    int off = 0;
    for (int t = 0; t < TYPES; ++t) {
      meta[16 + t] = off;
      off += ((meta[t] + 255) >> 8) << 8;   // pad each segment to 256 rows (BM=256)
    }
    meta[26] = off;                          // padded total
  }
}

__global__ void k_scatter(const int* __restrict__ types, int n,
                          int* __restrict__ meta, int* __restrict__ perm) {
  __shared__ int lc[TYPES], lbase[TYPES];
  if (threadIdx.x < TYPES) lc[threadIdx.x] = 0;
  __syncthreads();
  int i = blockIdx.x * 256 + threadIdx.x;
  int t = 0, loc = 0;
  bool ok = i < n;
  if (ok) { t = types[i]; loc = atomicAdd(&lc[t], 1); }
  __syncthreads();
  if (threadIdx.x < TYPES) {
    int c = lc[threadIdx.x];
    lbase[threadIdx.x] = c ? atomicAdd(&meta[32 + threadIdx.x], c) : 0;
  }
  __syncthreads();
  if (ok) perm[meta[16 + t] + lbase[t] + loc] = i;
}

// gather rows into sorted order, fp32 -> bf16; zero the padding rows
__global__ void k_gather(const float* __restrict__ x, const int* __restrict__ perm,
                         const int* __restrict__ meta, unsigned short* __restrict__ xs) {
  int p = blockIdx.x * 8 + (threadIdx.x >> 5);
  if (p >= meta[26]) return;
  int t = 0;
  while (p >= meta[17 + t]) t++;
  int e = (threadIdx.x & 31) * 4;
  unsigned short o0, o1, o2, o3;
  if (p - meta[16 + t] < meta[t]) {
    const float4 v = *(const float4*)(x + (size_t)perm[p] * D_IN + e);
    o0 = f2bf(v.x); o1 = f2bf(v.y); o2 = f2bf(v.z); o3 = f2bf(v.w);
  } else {
    o0 = o1 = o2 = o3 = 0;
  }
  *(ushort4*)(xs + (size_t)p * D_IN + e) = make_ushort4(o0, o1, o2, o3);
}

// W[t] (K x NOUT) fp32 -> Wt[t] (NOUT x K) bf16, 64x64 LDS tiles
__global__ void k_wtrans(const float* __restrict__ W, unsigned short* __restrict__ Wt,
                         int K, int NOUT) {
  int t = blockIdx.y;
  int ntn = NOUT >> 6;
  int kb = blockIdx.x / ntn, nb = blockIdx.x % ntn;
  __shared__ unsigned short tile[64][65];
  const float* src = W + (size_t)t * K * NOUT + (size_t)(kb * 64) * NOUT + nb * 64;
  int c = threadIdx.x & 63;
  int r0 = threadIdx.x >> 6;
  #pragma unroll
  for (int i = 0; i < 16; ++i) {
    int r = r0 * 16 + i;
    tile[r][c] = f2bf(src[(size_t)r * NOUT + c]);
  }
  __syncthreads();
  unsigned short* dst = Wt + (size_t)t * NOUT * K + (size_t)(nb * 64) * K + kb * 64;
  #pragma unroll
  for (int i = 0; i < 16; ++i) {
    int nn = r0 * 16 + i;
    dst[(size_t)nn * K + c] = tile[c][nn];
  }
}

// ---------------------------------------------------------------------------
// Grouped GEMM, 8-phase counted-vmcnt schedule, 256x256 tile, BK=64,
// 512 threads = 8 waves (2Mx4N), per-wave 128x64 output.
// LDS 128KB: A units [dbuf][mh] 16KB at 0..64K, B units [dbuf][nh] at 64K..128K.
// Snake quadrant order rel->(mh,nh): (0,0),(0,1),(1,1),(1,0) with register
// reuse: rel0 loads a(A0)+b(B0) [12 rds], rel1 b<-B1 [4], rel2 a<-A1 [8],
// rel3 b<-B0 [4] => 28 ds_read_b128/group (was 48).
// Unit last-LDS-read phases: A0@4kt+0, B1@4kt+1, A1@4kt+2, B0@4kt+3.
// Stage cadence (one unit/phase): rel0->A1(g+1), rel1->B0(g+1), rel2->B1(g+1),
// rel3->A0(g+2). Each restage is >=1 barrier-separated phase after its slot's
// last read (incl. dbuf parity: A0(g+2) shares buffer with A0(g), last read rel0).
// Group-end wait: vmcnt(2) (only A0(g+2) in flight), vmcnt(0) at tail.
// Raw s_barrier (never __syncthreads -> would drain vmcnt). XOR swizzle
// byte^=(lr&7)<<4 via pre-swizzled global source granule (0 conflicts, verified).
// Epilogue: C staged through LDS (re-used after full drain) for coalesced writes.
// ---------------------------------------------------------------------------
template <int K, int NOUT, bool RELU, bool FINAL>
__launch_bounds__(512, 2)
__global__ void k_gemm(const unsigned short* __restrict__ A,
                       const unsigned short* __restrict__ Wt,
                       const float* __restrict__ bias,
                       unsigned short* __restrict__ H,
                       float* __restrict__ OUT,
                       const int* __restrict__ meta,
                       const int* __restrict__ perm) {
  constexpr int nKT = K / 64;
  __shared__ char lds[131072];

  // bijective XCD-aware swizzle (m204)
  int NXB = gridDim.x;
  int nwg = NXB * (int)gridDim.y;
  int raw = blockIdx.x + blockIdx.y * NXB;
  int q = nwg >> 3, rr = nwg & 7;
  int xcd = raw & 7, idx = raw >> 3;
  int swz = (xcd < rr ? xcd * (q + 1) : rr * (q + 1) + (xcd - rr) * q) + idx;
  int bx = swz % NXB, by = swz / NXB;

  int row0 = by * 256;
  if (row0 >= meta[26]) return;          // block-uniform early exit (before any barrier)
  int t = 0;
  while (row0 >= meta[17 + t]) t++;      // segment offsets are multiples of 256
  int seg = meta[16 + t], cnt = meta[t];
  int tid = threadIdx.x, lane = tid & 63, wid = tid >> 6;
  int wr = (wid >> 2) * 128, wc = (wid & 3) * 64;
  int col0 = bx * 256;
  const char* Ag = (const char*)(A + (size_t)row0 * K);
  const char* Bg = (const char*)(Wt + ((size_t)t * NOUT + col0) * K);

  // staging: thread covers LDS bytes tid*16 (+8192 for j=1) of a unit.
  // LDS pos -> logical row lr = tid>>3, granule gl = tid&7; source granule gl^(lr&7).
  int gsrc = ((tid & 7) ^ ((tid >> 3) & 7)) * 16;
  const char* aS = Ag + (size_t)(tid >> 3) * (2 * K) + gsrc;
  const char* bS = Bg + (size_t)(((tid >> 3) & 31) + ((tid >> 3) >> 5) * 64) * (2 * K) + gsrc;

  // sub: 0=A0, 1=A1, 2=B0, 3=B1 (h = sub&1)
  auto stage = [&](int kt, int sub) {
    if (kt >= nKT) return;
    int h = sub & 1, du = kt & 1;
    char* dst = lds + ((sub < 2) ? 0 : 65536) + (du * 2 + h) * 16384 + wid * 1024;
    const char* src = (sub < 2 ? aS + (size_t)(h * 64) * (2 * K)
                               : bS + (size_t)(h * 32) * (2 * K)) + (size_t)kt * 128;
    async16(dst,        src);
    async16(dst + 8192, src + (size_t)128 * (2 * K));   // j=1: +128 rows / +128 cols
  };

  f32x4 acc[8][4] = {};
  int rA = lane & 15, qoff = (lane >> 4) * 16, xr = (lane & 7) << 4;
  int lrA = (wid >> 2) * 64;   // wave's A logical-row base
  int clB = (wid & 3) * 32;    // wave's B logical-col base

  // prologue, in schedule-phase order (vmcnt prefix semantics):
  stage(0, 0); stage(0, 1); stage(0, 2); stage(0, 3); stage(1, 0);
  asm volatile("s_waitcnt vmcnt(2)" ::: "memory");      // group 0's 4 units landed
  __builtin_amdgcn_s_barrier();

  for (int g = 0; g < nKT; ++g) {
    int d = g & 1;
    const char* Ad = lds + d * 32768;
    const char* Bd = lds + 65536 + d * 32768;
    bf16x8 a[4][2], b[2][2];
    #pragma unroll
    for (int rel = 0; rel < 4; ++rel) {
      constexpr int MH[4] = {0, 0, 1, 1};
      constexpr int NH[4] = {0, 1, 1, 0};
      const int mh = MH[rel], nh = NH[rel];
      if (rel == 0 || rel == 2) {          // A operand changed
        const char* Au = Ad + mh * 16384;
        #pragma unroll
        for (int m = 0; m < 4; ++m) {
          int lr = lrA + m * 16 + rA;
          #pragma unroll
          for (int kk = 0; kk < 2; ++kk)
            a[m][kk] = *(const bf16x8*)(Au + ((lr * 128 + kk * 64 + qoff) ^ xr));
        }
      }
      if (rel != 2) {                      // B operand changed (rel0:B0, rel1:B1, rel3:B0)
        const char* Bu = Bd + nh * 16384;
        #pragma unroll
        for (int nn = 0; nn < 2; ++nn) {
          int cl = clB + nn * 16 + rA;
          #pragma unroll
          for (int kk = 0; kk < 2; ++kk)
            b[nn][kk] = *(const bf16x8*)(Bu + ((cl * 128 + kk * 64 + qoff) ^ xr));
        }
      }
      if      (rel == 0) stage(g + 1, 1);   // A1(g+1): slot last read g-1 rel2
      else if (rel == 1) stage(g + 1, 2);   // B0(g+1): slot last read g-1 rel3
      else if (rel == 2) stage(g + 1, 3);   // B1(g+1): slot last read g-1 rel1
      else               stage(g + 2, 0);   // A0(g+2): slot last read g   rel0
      __builtin_amdgcn_s_barrier();
      asm volatile("s_waitcnt lgkmcnt(0)" ::: "memory");
      __builtin_amdgcn_sched_barrier(0);    // rule 18: pin MFMA after the wait
      __builtin_amdgcn_s_setprio(1);
      #pragma unroll
      for (int kk = 0; kk < 2; ++kk)
        #pragma unroll
        for (int m = 0; m < 4; ++m)
          #pragma unroll
          for (int nn = 0; nn < 2; ++nn)
            acc[mh * 4 + m][nh * 2 + nn] = __builtin_amdgcn_mfma_f32_16x16x32_bf16(
                a[m][kk], b[nn][kk], acc[mh * 4 + m][nh * 2 + nn], 0, 0, 0);
      __builtin_amdgcn_s_setprio(0);
      if (rel == 3 && g + 1 < nKT) {
        if (g + 2 < nKT) asm volatile("s_waitcnt vmcnt(2)" ::: "memory");
        else             asm volatile("s_waitcnt vmcnt(0)" ::: "memory");
      }
      __builtin_amdgcn_s_barrier();
    }
  }
  // loop exit: all vmem drained (tail vmcnt(0) at g=nKT-2), all waves past their
  // lgkmcnt(0) and the final barrier -> LDS is free for the epilogue.

  // epilogue: acc -> LDS (XOR-swizzled 16B granules, 2-way max) -> coalesced stores.
  // D mapping col=lane&15, row=(lane>>4)*4+e (measured, learn_hip m89/m91).
  int cA = lane & 15, rE = (lane >> 4) * 4;
  float bv[4];
  #pragma unroll
  for (int ni = 0; ni < 4; ++ni) bv[ni] = bias[t * NOUT + col0 + wc + ni * 16 + cA];
  char* cb = (char*)lds;

  if (!FINAL) {
    // 256 rows x 256 bf16 cols = 128KB
    #pragma unroll
    for (int mi = 0; mi < 8; ++mi)
      #pragma unroll
      for (int e = 0; e < 4; ++e) {
        int row = wr + mi * 16 + rE + e;
        int sw = (row & 7) << 4;
        #pragma unroll
        for (int ni = 0; ni < 4; ++ni) {
          float v = acc[mi][ni][e] + bv[ni];
          if (RELU) v = fmaxf(v, 0.f);
          int col = wc + ni * 16 + cA;
          *(unsigned short*)(cb + ((row * 512 + col * 2) ^ sw)) = f2bf(v);
        }
      }
    __builtin_amdgcn_s_barrier();
    #pragma unroll 4
    for (int r = 0; r < 16; ++r) {
      int row = wid * 32 + r * 2 + (lane >> 5);
      int addr = row * 512 + ((((lane & 31) * 16)) ^ ((row & 7) << 4));
      bf16x8 v = *(const bf16x8*)(cb + addr);
      *(bf16x8*)(H + (size_t)(row0 + row) * NOUT + col0 + (lane & 31) * 8) = v;
    }
  } else {
    // f32 out, two column-half passes (256 rows x 128 f32 = 128KB each)
    int myhalf = (wid & 3) >> 1;
    #pragma unroll
    for (int p = 0; p < 2; ++p) {
      if (myhalf == p) {
        int colh = wc & 127;
        #pragma unroll
        for (int mi = 0; mi < 8; ++mi)
          #pragma unroll
          for (int e = 0; e < 4; ++e) {
            int row = wr + mi * 16 + rE + e;
            int sw = (row & 7) << 4;
            #pragma unroll
            for (int ni = 0; ni < 4; ++ni) {
              float v = acc[mi][ni][e] + bv[ni];
              if (RELU) v = fmaxf(v, 0.f);
              int col = colh + ni * 16 + cA;
              *(float*)(cb + ((row * 512 + col * 4) ^ sw)) = v;
            }
          }
      }
      __builtin_amdgcn_s_barrier();
      #pragma unroll 4
      for (int r = 0; r < 16; ++r) {
        int row = wid * 32 + r * 2 + (lane >> 5);
        int gr = row0 + row;
        int addr = row * 512 + ((((lane & 31) * 16)) ^ ((row & 7) << 4));
        float4 v = *(const float4*)(cb + addr);
        if (gr - seg < cnt) {
          int pr = perm[gr];
          *(float4*)(OUT + (size_t)pr * NOUT + p * (NOUT / 2) + (lane & 31) * 4) = v;
        }
      }
      if (p == 0) __builtin_amdgcn_s_barrier();  // before pass 1 overwrites LDS
    }
  }
}

extern "C" void kernel_launch(void* const* d_in, const int* in_sizes, int n_in,
                              void* d_out, int out_size, void* d_ws, size_t ws_size,
                              hipStream_t stream) {
  const float* x     = (const float*)d_in[0];
  const int*   types = (const int*)d_in[1];
  const float* W0    = (const float*)d_in[2];
  const float* b0    = (const float*)d_in[3];
  const float* W1    = (const float*)d_in[4];
  const float* b1    = (const float*)d_in[5];
  const float* W2    = (const float*)d_in[6];
  const float* b2    = (const float*)d_in[7];
  float* out = (float*)d_out;
  int n = in_sizes[1];
  int RB = (n + 255) / 256 + TYPES;       // worst-case padded 256-row blocks
  size_t NPAD = (size_t)RB * 256;

  char* ws = (char*)d_ws;
  int* meta = (int*)ws;
  int* perm = (int*)(ws + 1024);
  size_t off = 1024 + NPAD * 4;
  off = (off + 255) & ~(size_t)255;
  unsigned short* wt0 = (unsigned short*)(ws + off); off += (size_t)TYPES * D_H1 * D_IN * 2;
  unsigned short* wt1 = (unsigned short*)(ws + off); off += (size_t)TYPES * D_H2 * D_H1 * 2;
  unsigned short* wt2 = (unsigned short*)(ws + off); off += (size_t)TYPES * D_OUT * D_H2 * 2;
  off = (off + 255) & ~(size_t)255;
  unsigned short* B1 = (unsigned short*)(ws + off); off += NPAD * 512 * 2;  // xs, later h2
  unsigned short* B2 = (unsigned short*)(ws + off); off += NPAD * 512 * 2;  // h1

  int hb = (n + 255) / 256;
  k_init<<<1, 64, 0, stream>>>(meta);
  k_hist<<<hb, 256, 0, stream>>>(types, n, meta);
  k_scan<<<1, 64, 0, stream>>>(meta);
  k_scatter<<<hb, 256, 0, stream>>>(types, n, meta, perm);
  k_gather<<<RB * 32, 256, 0, stream>>>(x, perm, meta, B1);
  k_wtrans<<<dim3((D_IN / 64) * (D_H1 / 64), TYPES), 256, 0, stream>>>(W0, wt0, D_IN, D_H1);
  k_wtrans<<<dim3((D_H1 / 64) * (D_H2 / 64), TYPES), 256, 0, stream>>>(W1, wt1, D_H1, D_H2);
  k_wtrans<<<dim3((D_H2 / 64) * (D_OUT / 64), TYPES), 256, 0, stream>>>(W2, wt2, D_H2, D_OUT);

  k_gemm<D_IN, D_H1, true,  false><<<dim3(D_H1 / 256, RB), 512, 0, stream>>>(B1, wt0, b0, B2, nullptr, meta, perm);
  k_gemm<D_H1, D_H2, true,  false><<<dim3(D_H2 / 256, RB), 512, 0, stream>>>(B2, wt1, b1, B1, nullptr, meta, perm);
  k_gemm<D_H2, D_OUT, false, true ><<<dim3(D_OUT / 256, RB), 512, 0, stream>>>(B1, wt2, b2, nullptr, out, meta, perm);
}

// Round 8
// 423.942 us; speedup vs baseline: 1.4120x; 1.0275x over previous
//
#include <hip/hip_runtime.h>
#include <stdint.h>

typedef float  f32x4  __attribute__((ext_vector_type(4)));
typedef short  bf16x8 __attribute__((ext_vector_type(8)));

#define TYPES 10
#define D_IN  128
#define D_H1  512
#define D_H2  512
#define D_OUT 256

__device__ __forceinline__ unsigned short f2bf(float f) {
  union { float f; unsigned u; } v; v.f = f;
  unsigned u = v.u;
  return (unsigned short)((u + 0x7FFFu + ((u >> 16) & 1u)) >> 16);  // RTNE
}

__device__ __forceinline__ void async16(void* lds, const void* g) {
  __builtin_amdgcn_global_load_lds(
      (const __attribute__((address_space(1))) void*)g,
      (__attribute__((address_space(3))) void*)lds, 16, 0, 0);
}

// meta layout (ints): [0..9] counts, [16..26] padded offsets (offs[10]=total), [32..41] scatter cursors
__global__ void k_init(int* meta) {
  if (threadIdx.x < 48) meta[threadIdx.x] = 0;
}

__global__ void k_hist(const int* __restrict__ types, int n, int* __restrict__ meta) {
  __shared__ int lc[TYPES];
  if (threadIdx.x < TYPES) lc[threadIdx.x] = 0;
  __syncthreads();
  int i = blockIdx.x * 256 + threadIdx.x;
  if (i < n) atomicAdd(&lc[types[i]], 1);
  __syncthreads();
  if (threadIdx.x < TYPES && lc[threadIdx.x]) atomicAdd(&meta[threadIdx.x], lc[threadIdx.x]);
}

__global__ void k_scan(int* meta) {
  if (threadIdx.x == 0) {
    int off = 0;
    for (int t = 0; t < TYPES; ++t) {
      meta[16 + t] = off;
      off += ((meta[t] + 255) >> 8) << 8;   // pad each segment to 256 rows (BM=256)
    }
    meta[26] = off;                          // padded total
  }
}

__global__ void k_scatter(const int* __restrict__ types, int n,
                          int* __restrict__ meta, int* __restrict__ perm) {
  __shared__ int lc[TYPES], lbase[TYPES];
  if (threadIdx.x < TYPES) lc[threadIdx.x] = 0;
  __syncthreads();
  int i = blockIdx.x * 256 + threadIdx.x;
  int t = 0, loc = 0;
  bool ok = i < n;
  if (ok) { t = types[i]; loc = atomicAdd(&lc[t], 1); }
  __syncthreads();
  if (threadIdx.x < TYPES) {
    int c = lc[threadIdx.x];
    lbase[threadIdx.x] = c ? atomicAdd(&meta[32 + threadIdx.x], c) : 0;
  }
  __syncthreads();
  if (ok) perm[meta[16 + t] + lbase[t] + loc] = i;
}

// gather rows into sorted order, fp32 -> bf16; zero the padding rows
__global__ void k_gather(const float* __restrict__ x, const int* __restrict__ perm,
                         const int* __restrict__ meta, unsigned short* __restrict__ xs) {
  int p = blockIdx.x * 8 + (threadIdx.x >> 5);
  if (p >= meta[26]) return;
  int t = 0;
  while (p >= meta[17 + t]) t++;
  int e = (threadIdx.x & 31) * 4;
  unsigned short o0, o1, o2, o3;
  if (p - meta[16 + t] < meta[t]) {
    const float4 v = *(const float4*)(x + (size_t)perm[p] * D_IN + e);
    o0 = f2bf(v.x); o1 = f2bf(v.y); o2 = f2bf(v.z); o3 = f2bf(v.w);
  } else {
    o0 = o1 = o2 = o3 = 0;
  }
  *(ushort4*)(xs + (size_t)p * D_IN + e) = make_ushort4(o0, o1, o2, o3);
}

// All three weight transposes in one launch: W[t] (K x NOUT) fp32 -> Wt[t] (NOUT x K) bf16
__global__ void k_wtrans_all(const float* __restrict__ W0a, const float* __restrict__ W1a,
                             const float* __restrict__ W2a,
                             unsigned short* __restrict__ wt0, unsigned short* __restrict__ wt1,
                             unsigned short* __restrict__ wt2) {
  int b = blockIdx.x;
  const float* W; unsigned short* Wt; int K, NOUT, t, local;
  if (b < 160)      { W = W0a; Wt = wt0; K = 128; NOUT = 512; t = b / 16; local = b % 16; }
  else if (b < 800) { b -= 160; W = W1a; Wt = wt1; K = 512; NOUT = 512; t = b / 64; local = b % 64; }
  else              { b -= 800; W = W2a; Wt = wt2; K = 512; NOUT = 256; t = b / 32; local = b % 32; }
  int ntn = NOUT >> 6;
  int kb = local / ntn, nb = local % ntn;
  __shared__ unsigned short tile[64][65];
  const float* src = W + (size_t)t * K * NOUT + (size_t)(kb * 64) * NOUT + nb * 64;
  int c = threadIdx.x & 63;
  int r0 = threadIdx.x >> 6;
  #pragma unroll
  for (int i = 0; i < 16; ++i) {
    int r = r0 * 16 + i;
    tile[r][c] = f2bf(src[(size_t)r * NOUT + c]);
  }
  __syncthreads();
  unsigned short* dst = Wt + (size_t)t * NOUT * K + (size_t)(nb * 64) * K + kb * 64;
  #pragma unroll
  for (int i = 0; i < 16; ++i) {
    int nn = r0 * 16 + i;
    dst[(size_t)nn * K + c] = tile[c][nn];
  }
}

// ---------------------------------------------------------------------------
// Grouped GEMM, 8-phase counted-vmcnt schedule, 256x256 tile, BK=64,
// 512 threads = 8 waves (2Mx4N), per-wave 128x64 output.
// LDS 128KB: A units [dbuf][mh] 16KB at 0..64K, B units [dbuf][nh] at 64K..128K.
// Snake quadrant order rel->(mh,nh): (0,0),(0,1),(1,1),(1,0).
// REGISTER PLAN (R8 fix of the R6/R7 bug): a[4][2] holds A0 (rel0) then A1
// (rel2); b0[2][2] holds B0 (loaded rel0, used rel0 AND rel3); b1[2][2] holds
// B1 (loaded rel1, used rel1/rel2). R6/R7 used ONE b set -> rel3 computed
// A1*B1 instead of A1*B0 (deterministic absmax 4.09). 24 ds_read_b128/group.
// LDS unit last-read phases: A0@rel0, B0@rel0, B1@rel1, A1@rel2.
// Stage cadence (deep slack): rel0 -> A1(g+1)+B0(g+1); rel1 -> B1(g+1);
// rel3 -> A0(g+2). Issue-to-need slack >=4 phases for every unit.
// FIFO waits (simulated nKT=2 and 8, incl. tails): prologue vmcnt(4);
// end-rel0 vmcnt(6) drains exactly B1(g) (tail: 0); end-rel3 vmcnt(4) drains
// A0(g+1),A1(g+1),B0(g+1) (tail: 2). Restage-vs-last-read gaps >=2 phases.
// SYNC: raw s_barrier is NOT an IR fence; two sched_barrier(0) pins per phase
// confine ds_reads between the previous end-barrier and the mid-phase lgkmcnt.
// XOR swizzle byte^=(lr&7)<<4 via pre-swizzled global source (0 conflicts).
// Epilogue: C staged through LDS (after full drain) for coalesced writes.
// ---------------------------------------------------------------------------
template <int K, int NOUT, bool RELU, bool FINAL>
__launch_bounds__(512, 2)
__global__ void k_gemm(const unsigned short* __restrict__ A,
                       const unsigned short* __restrict__ Wt,
                       const float* __restrict__ bias,
                       unsigned short* __restrict__ H,
                       float* __restrict__ OUT,
                       const int* __restrict__ meta,
                       const int* __restrict__ perm) {
  constexpr int nKT = K / 64;
  __shared__ char lds[131072];

  // bijective XCD-aware swizzle (m204)
  int NXB = gridDim.x;
  int nwg = NXB * (int)gridDim.y;
  int raw = blockIdx.x + blockIdx.y * NXB;
  int q = nwg >> 3, rr = nwg & 7;
  int xcd = raw & 7, idx = raw >> 3;
  int swz = (xcd < rr ? xcd * (q + 1) : rr * (q + 1) + (xcd - rr) * q) + idx;
  int bx = swz % NXB, by = swz / NXB;

  int row0 = by * 256;
  if (row0 >= meta[26]) return;          // block-uniform early exit (before any barrier)
  int t = 0;
  while (row0 >= meta[17 + t]) t++;      // segment offsets are multiples of 256
  int seg = meta[16 + t], cnt = meta[t];
  int tid = threadIdx.x, lane = tid & 63, wid = tid >> 6;
  int wr = (wid >> 2) * 128, wc = (wid & 3) * 64;
  int col0 = bx * 256;
  const char* Ag = (const char*)(A + (size_t)row0 * K);
  const char* Bg = (const char*)(Wt + ((size_t)t * NOUT + col0) * K);

  // staging: thread covers LDS bytes tid*16 (+8192 for j=1) of a unit.
  // LDS pos -> logical row lr = tid>>3, granule gl = tid&7; source granule gl^(lr&7).
  int gsrc = ((tid & 7) ^ ((tid >> 3) & 7)) * 16;
  const char* aS = Ag + (size_t)(tid >> 3) * (2 * K) + gsrc;
  const char* bS = Bg + (size_t)(((tid >> 3) & 31) + ((tid >> 3) >> 5) * 64) * (2 * K) + gsrc;

  // sub: 0=A0, 1=A1, 2=B0, 3=B1 (h = sub&1)
  auto stage = [&](int kt, int sub) {
    if (kt >= nKT) return;
    int h = sub & 1, du = kt & 1;
    char* dst = lds + ((sub < 2) ? 0 : 65536) + (du * 2 + h) * 16384 + wid * 1024;
    const char* src = (sub < 2 ? aS + (size_t)(h * 64) * (2 * K)
                               : bS + (size_t)(h * 32) * (2 * K)) + (size_t)kt * 128;
    async16(dst,        src);
    async16(dst + 8192, src + (size_t)128 * (2 * K));   // j=1: +128 rows / +128 cols
  };

  f32x4 acc[8][4] = {};
  int rA = lane & 15, qoff = (lane >> 4) * 16, xr = (lane & 7) << 4;
  int lrA = (wid >> 2) * 64;   // wave's A logical-row base
  int clB = (wid & 3) * 32;    // wave's B logical-col base

  // prologue (FIFO order): A0(0),A1(0),B0(0),B1(0),A0(1); rel0(0) needs
  // A0(0),B0(0) -> drain through B0(0), leave B1(0)+A0(1) -> vmcnt(4).
  stage(0, 0); stage(0, 1); stage(0, 2); stage(0, 3); stage(1, 0);
  asm volatile("s_waitcnt vmcnt(4)" ::: "memory");
  __builtin_amdgcn_s_barrier();

  for (int g = 0; g < nKT; ++g) {
    int d = g & 1;
    const char* Ad = lds + d * 32768;
    const char* Bd = lds + 65536 + d * 32768;
    bf16x8 a[4][2], b0[2][2], b1[2][2];
    #pragma unroll
    for (int rel = 0; rel < 4; ++rel) {
      __builtin_amdgcn_sched_barrier(0);   // pin reads BELOW the preceding barrier
      constexpr int MH[4] = {0, 0, 1, 1};
      constexpr int NH[4] = {0, 1, 1, 0};
      const int mh = MH[rel], nh = NH[rel];
      if (rel == 0 || rel == 2) {          // A operand: A0 at rel0, A1 at rel2
        const char* Au = Ad + mh * 16384;
        #pragma unroll
        for (int m = 0; m < 4; ++m) {
          int lr = lrA + m * 16 + rA;
          #pragma unroll
          for (int kk = 0; kk < 2; ++kk)
            a[m][kk] = *(const bf16x8*)(Au + ((lr * 128 + kk * 64 + qoff) ^ xr));
        }
      }
      if (rel == 0) {                      // B0 -> b0 (used rel0 and rel3)
        const char* Bu = Bd;
        #pragma unroll
        for (int nn = 0; nn < 2; ++nn) {
          int cl = clB + nn * 16 + rA;
          #pragma unroll
          for (int kk = 0; kk < 2; ++kk)
            b0[nn][kk] = *(const bf16x8*)(Bu + ((cl * 128 + kk * 64 + qoff) ^ xr));
        }
      }
      if (rel == 1) {                      // B1 -> b1 (used rel1 and rel2)
        const char* Bu = Bd + 16384;
        #pragma unroll
        for (int nn = 0; nn < 2; ++nn) {
          int cl = clB + nn * 16 + rA;
          #pragma unroll
          for (int kk = 0; kk < 2; ++kk)
            b1[nn][kk] = *(const bf16x8*)(Bu + ((cl * 128 + kk * 64 + qoff) ^ xr));
        }
      }
      if      (rel == 0) { stage(g + 1, 1); stage(g + 1, 2); }  // A1(g+1), B0(g+1)
      else if (rel == 1) stage(g + 1, 3);                        // B1(g+1)
      else if (rel == 3) stage(g + 2, 0);                        // A0(g+2)
      __builtin_amdgcn_s_barrier();
      asm volatile("s_waitcnt lgkmcnt(0)" ::: "memory");
      __builtin_amdgcn_sched_barrier(0);   // pin MFMA below the wait (rule 18)
      __builtin_amdgcn_s_setprio(1);
      #pragma unroll
      for (int kk = 0; kk < 2; ++kk)
        #pragma unroll
        for (int m = 0; m < 4; ++m)
          #pragma unroll
          for (int nn = 0; nn < 2; ++nn) {
            const bf16x8 bop = nh ? b1[nn][kk] : b0[nn][kk];   // compile-time select
            acc[mh * 4 + m][nh * 2 + nn] = __builtin_amdgcn_mfma_f32_16x16x32_bf16(
                a[m][kk], bop, acc[mh * 4 + m][nh * 2 + nn], 0, 0, 0);
          }
      __builtin_amdgcn_s_setprio(0);
      if (rel == 0) {                       // cover B1(g) for rel1
        if (g + 1 < nKT) asm volatile("s_waitcnt vmcnt(6)" ::: "memory");
        else             asm volatile("s_waitcnt vmcnt(0)" ::: "memory");
      } else if (rel == 3 && g + 1 < nKT) { // cover A0(g+1),B0(g+1) for rel0
        if (g + 2 < nKT) asm volatile("s_waitcnt vmcnt(4)" ::: "memory");
        else             asm volatile("s_waitcnt vmcnt(2)" ::: "memory");
      }
      __builtin_amdgcn_s_barrier();
    }
  }
  // loop exit: vmcnt(0) done at end-rel0 of the last group; all waves past the
  // final barrier -> LDS free for the epilogue.

  // epilogue: acc -> LDS (XOR-swizzled 16B granules) -> coalesced stores.
  // D mapping col=lane&15, row=(lane>>4)*4+e (measured, learn_hip m89/m91).
  int cA = lane & 15, rE = (lane >> 4) * 4;
  float bv[4];
  #pragma unroll
  for (int ni = 0; ni < 4; ++ni) bv[ni] = bias[t * NOUT + col0 + wc + ni * 16 + cA];
  char* cb = (char*)lds;

  if (!FINAL) {
    // 256 rows x 256 bf16 cols = 128KB
    #pragma unroll
    for (int mi = 0; mi < 8; ++mi)
      #pragma unroll
      for (int e = 0; e < 4; ++e) {
        int row = wr + mi * 16 + rE + e;
        int sw = (row & 7) << 4;
        #pragma unroll
        for (int ni = 0; ni < 4; ++ni) {
          float v = acc[mi][ni][e] + bv[ni];
          if (RELU) v = fmaxf(v, 0.f);
          int col = wc + ni * 16 + cA;
          *(unsigned short*)(cb + ((row * 512 + col * 2) ^ sw)) = f2bf(v);
        }
      }
    __builtin_amdgcn_s_barrier();
    #pragma unroll 4
    for (int r = 0; r < 16; ++r) {
      int row = wid * 32 + r * 2 + (lane >> 5);
      int addr = row * 512 + ((((lane & 31) * 16)) ^ ((row & 7) << 4));
      bf16x8 v = *(const bf16x8*)(cb + addr);
      *(bf16x8*)(H + (size_t)(row0 + row) * NOUT + col0 + (lane & 31) * 8) = v;
    }
  } else {
    // f32 out, two column-half passes (256 rows x 128 f32 = 128KB each)
    int myhalf = (wid & 3) >> 1;
    #pragma unroll
    for (int p = 0; p < 2; ++p) {
      if (myhalf == p) {
        int colh = wc & 127;
        #pragma unroll
        for (int mi = 0; mi < 8; ++mi)
          #pragma unroll
          for (int e = 0; e < 4; ++e) {
            int row = wr + mi * 16 + rE + e;
            int sw = (row & 7) << 4;
            #pragma unroll
            for (int ni = 0; ni < 4; ++ni) {
              float v = acc[mi][ni][e] + bv[ni];
              if (RELU) v = fmaxf(v, 0.f);
              int col = colh + ni * 16 + cA;
              *(float*)(cb + ((row * 512 + col * 4) ^ sw)) = v;
            }
          }
      }
      __builtin_amdgcn_s_barrier();
      #pragma unroll 4
      for (int r = 0; r < 16; ++r) {
        int row = wid * 32 + r * 2 + (lane >> 5);
        int gr = row0 + row;
        int addr = row * 512 + ((((lane & 31) * 16)) ^ ((row & 7) << 4));
        float4 v = *(const float4*)(cb + addr);
        if (gr - seg < cnt) {
          int pr = perm[gr];
          *(float4*)(OUT + (size_t)pr * NOUT + p * (NOUT / 2) + (lane & 31) * 4) = v;
        }
      }
      if (p == 0) __builtin_amdgcn_s_barrier();  // before pass 1 overwrites LDS
    }
  }
}

extern "C" void kernel_launch(void* const* d_in, const int* in_sizes, int n_in,
                              void* d_out, int out_size, void* d_ws, size_t ws_size,
                              hipStream_t stream) {
  const float* x     = (const float*)d_in[0];
  const int*   types = (const int*)d_in[1];
  const float* W0    = (const float*)d_in[2];
  const float* b0    = (const float*)d_in[3];
  const float* W1    = (const float*)d_in[4];
  const float* b1    = (const float*)d_in[5];
  const float* W2    = (const float*)d_in[6];
  const float* b2    = (const float*)d_in[7];
  float* out = (float*)d_out;
  int n = in_sizes[1];
  int RB = (n + 255) / 256 + TYPES;       // worst-case padded 256-row blocks
  size_t NPAD = (size_t)RB * 256;

  char* ws = (char*)d_ws;
  int* meta = (int*)ws;
  int* perm = (int*)(ws + 1024);
  size_t off = 1024 + NPAD * 4;
  off = (off + 255) & ~(size_t)255;
  unsigned short* wt0 = (unsigned short*)(ws + off); off += (size_t)TYPES * D_H1 * D_IN * 2;
  unsigned short* wt1 = (unsigned short*)(ws + off); off += (size_t)TYPES * D_H2 * D_H1 * 2;
  unsigned short* wt2 = (unsigned short*)(ws + off); off += (size_t)TYPES * D_OUT * D_H2 * 2;
  off = (off + 255) & ~(size_t)255;
  unsigned short* B1 = (unsigned short*)(ws + off); off += NPAD * 512 * 2;  // xs, later h2
  unsigned short* B2 = (unsigned short*)(ws + off); off += NPAD * 512 * 2;  // h1

  int hb = (n + 255) / 256;
  k_init<<<1, 64, 0, stream>>>(meta);
  k_hist<<<hb, 256, 0, stream>>>(types, n, meta);
  k_scan<<<1, 64, 0, stream>>>(meta);
  k_scatter<<<hb, 256, 0, stream>>>(types, n, meta, perm);
  k_gather<<<RB * 32, 256, 0, stream>>>(x, perm, meta, B1);
  k_wtrans_all<<<1120, 256, 0, stream>>>(W0, W1, W2, wt0, wt1, wt2);

  k_gemm<D_IN, D_H1, true,  false><<<dim3(D_H1 / 256, RB), 512, 0, stream>>>(B1, wt0, b0, B2, nullptr, meta, perm);
  k_gemm<D_H1, D_H2, true,  false><<<dim3(D_H2 / 256, RB), 512, 0, stream>>>(B2, wt1, b1, B1, nullptr, meta, perm);
  k_gemm<D_H2, D_OUT, false, true ><<<dim3(D_OUT / 256, RB), 512, 0, stream>>>(B1, wt2, b2, nullptr, out, meta, perm);
}